// Round 1
// baseline (611.932 us; speedup 1.0000x reference)
//
#include <hip/hip_runtime.h>
#include <hip/hip_bf16.h>

// R-GCN v4: gemm re-tiled for read-once A + software pipeline.
//  - 512-thread blocks, 128 rows x 256 cols output (dual-group acc unchanged
//    at 128 f32/thread). nt split removed -> A fp32 read ONCE (256 MB logical,
//    was 512 MB).
//  - BK=32, double-buffered LDS (As 2x8KB + Bs 2x32KB = 80 KB), ONE barrier
//    per kt: stage(kt+1) issued before compute(kt) in the same region, so the
//    vmcnt/lgkm drain at __syncthreads is the pipeline boundary, not a stall.
//  - split-K=4 -> 512 blocks; bijective XCD swizzle clusters each p's 128
//    blocks on an XCD pair so its 4MB B panel stays L2-resident.
//  - LDS XOR swizzle g ^= (row>>1)&3 at 64B row stride (write side via
//    pre-swizzled global src, read side same involution).
// Stages 1/2, colsum, zero, reduce, prep, workspace layout: unchanged.

typedef __bf16 bf16x8 __attribute__((ext_vector_type(8)));
typedef float floatx4 __attribute__((ext_vector_type(4)));
using bf16 = __hip_bfloat16;

#define LDK 72   // stage1 LDS pad

__device__ __forceinline__ float b2f(bf16 x){ return __bfloat162float(x); }
__device__ __forceinline__ bf16 f2b(float f){ return __float2bfloat16(f); }
__device__ __forceinline__ float rawb2f(unsigned short u){
  unsigned int x = ((unsigned int)u) << 16; float f; __builtin_memcpy(&f,&x,4); return f;
}
__device__ __forceinline__ unsigned short f2bu(float f){
  bf16 h = __float2bfloat16(f); unsigned short u; __builtin_memcpy(&u,&h,2); return u;
}
__device__ __forceinline__ uint4 cvt8(float4 a, float4 b){
  unsigned short u[8] = {f2bu(a.x),f2bu(a.y),f2bu(a.z),f2bu(a.w),
                         f2bu(b.x),f2bu(b.y),f2bu(b.z),f2bu(b.w)};
  uint4 v; __builtin_memcpy(&v,u,16); return v;
}
// async global->LDS, 16B per lane; lds dest = wave-uniform base + lane*16
__device__ __forceinline__ void async_ld16(const void* gp, void* lp){
  typedef __attribute__((address_space(1))) const unsigned int GU;
  typedef __attribute__((address_space(3))) unsigned int LU;
  __builtin_amdgcn_global_load_lds((GU*)(unsigned long long)gp,
                                   (LU*)(unsigned int)(unsigned long long)lp,
                                   16, 0, 0);
}

// ---------------------------------------------------------------- prep ------
__global__ void prep_kernel(const float* __restrict__ m_co_deg, const float* __restrict__ d_co_deg,
                            const float* __restrict__ m_d_degree, const float* __restrict__ d_m_degree,
                            const float* __restrict__ Wx, const float* __restrict__ bx,
                            float* __restrict__ scal, float* __restrict__ Sbuf, float* __restrict__ bSbuf)
{
  const int i = blockIdx.x*blockDim.x + threadIdx.x;
  if (i < 4096){
    scal[0*4096+i] = rsqrtf(m_co_deg[2*i]);
    scal[1*4096+i] = rsqrtf(m_co_deg[2*i+1]);
    scal[2*4096+i] = 0.5f / m_d_degree[i];
    scal[3*4096+i] = rsqrtf(d_co_deg[2*i]);
    scal[4*4096+i] = rsqrtf(d_co_deg[2*i+1]);
    scal[5*4096+i] = 0.5f / d_m_degree[i];
  }
  const int pa[4] = {0,2,3,6}, pb[4] = {1,5,4,7};
  if (i < 65536){
    #pragma unroll
    for (int s=0;s<4;s++)
      Sbuf[s*65536+i] = Wx[pa[s]*65536+i] + Wx[pb[s]*65536+i];
  }
  if (i < 256){
    #pragma unroll
    for (int s=0;s<4;s++)
      bSbuf[s*256+i] = bx[pa[s]*256+i] + bx[pb[s]*256+i];
  }
}

// -------------------------------------------------------------- stage 1 -----
__global__ __launch_bounds__(256) void stage1_kernel(
    const float* __restrict__ feat, const float* __restrict__ Wm, const float* __restrict__ bm,
    const float* __restrict__ Wd, const float* __restrict__ bd,
    const float* __restrict__ Sbuf, const float* __restrict__ bSbuf, const float* __restrict__ scal,
    bf16* __restrict__ BHm, bf16* __restrict__ BHd,
    float* __restrict__ L0m, float* __restrict__ L0d,
    float* __restrict__ L2nm, float* __restrict__ L2nd,
    bf16* __restrict__ Tm, bf16* __restrict__ Td)
{
  __shared__ __align__(16) bf16 As[128*LDK];
  __shared__ __align__(16) bf16 Bs[128*LDK];
  const int p = blockIdx.y;
  const int side = p >> 3, widx = p & 7;
  const int bx_ = blockIdx.x;
  const bool modeT = (widx != 0 && widx != 7);
  const float* X = feat + (size_t)side*(4096*256);
  const float* Wb = side ? Wd : Wm;
  const float* W = (widx==0) ? Wb : (widx==7) ? (Wb + 2*65536)
                 : (widx<=2) ? (Wb + widx*65536) : (Sbuf + (widx-3)*65536);
  int rt, ct;
  if (!modeT){ rt = bx_>>1; ct = bx_&1; } else { rt = bx_&1; ct = bx_>>1; }
  const float* Amat = modeT ? W : X;
  const float* Bmat = modeT ? X : W;
  const int arow0 = rt*128, brow0 = ct*128;
  const int tid = threadIdx.x;
  const int lane = tid & 63, wv = tid>>6;
  const int wr = wv>>1, wc = wv&1, q = lane>>4, l15 = lane&15;

  floatx4 acc[4][4];
  #pragma unroll
  for (int i=0;i<4;i++)
    #pragma unroll
    for (int j=0;j<4;j++)
      #pragma unroll
      for (int r=0;r<4;r++) acc[i][j][r] = 0.f;

  for (int kt=0; kt<4; kt++){
    const int c0 = kt*64;
    __syncthreads();
    #pragma unroll
    for (int i=0;i<4;i++){
      const int id = tid + i*256;
      const int row = id>>3, kg = id&7;
      const float* ap = Amat + (size_t)(arow0+row)*256 + c0 + kg*8;
      const float* bp = Bmat + (size_t)(brow0+row)*256 + c0 + kg*8;
      float4 a0 = *(const float4*)ap, a1 = *(const float4*)(ap+4);
      float4 b0 = *(const float4*)bp, b1 = *(const float4*)(bp+4);
      *(uint4*)(&As[row*LDK + kg*8]) = cvt8(a0,a1);
      *(uint4*)(&Bs[row*LDK + kg*8]) = cvt8(b0,b1);
    }
    __syncthreads();
    #pragma unroll
    for (int ki=0; ki<2; ki++){
      bf16x8 af[4], bg[4];
      #pragma unroll
      for (int i=0;i<4;i++) af[i] = *(const bf16x8*)&As[(wr*64 + i*16 + l15)*LDK + ki*32 + q*8];
      #pragma unroll
      for (int j=0;j<4;j++) bg[j] = *(const bf16x8*)&Bs[(wc*64 + j*16 + l15)*LDK + ki*32 + q*8];
      #pragma unroll
      for (int i=0;i<4;i++)
        #pragma unroll
        for (int j=0;j<4;j++)
          acc[i][j] = __builtin_amdgcn_mfma_f32_16x16x32_bf16(af[i], bg[j], acc[i][j], 0,0,0);
    }
  }

  const float* bb = side ? bd : bm;
  const float* bias = (widx==0) ? bb : (widx==7) ? (bb + 512)
                    : (widx<=2) ? (bb + widx*256) : (bSbuf + (widx-3)*256);
  float* outF = nullptr; bf16* outB = nullptr; int pitch = 256; const float* scl = nullptr;
  if (widx==0){ outF = side? L0d : L0m; }
  else if (widx==7){ outF = side? L2nd : L2nm; }
  else if (widx==1){ outB = side? BHd : BHm; pitch = 4096; scl = scal + side*12288; }
  else if (widx==2){ outB = (side? BHd : BHm) + 256*4096; pitch = 4096; scl = scal + side*12288 + 4096; }
  else { outB = (side? Td : Tm) + (widx-3)*(256*4096); pitch = 4096; }

  #pragma unroll
  for (int i=0;i<4;i++){
    #pragma unroll
    for (int j=0;j<4;j++){
      const int gcol = brow0 + wc*64 + j*16 + l15;
      #pragma unroll
      for (int r=0;r<4;r++){
        const int grow = arow0 + wr*64 + i*16 + q*4 + r;
        float v = acc[i][j][r];
        const int nidx = modeT ? grow : gcol;
        v += bias[nidx];
        if (scl) v *= scl[gcol];
        if (outF) outF[(size_t)grow*pitch + gcol] = v;
        else      outB[(size_t)grow*pitch + gcol] = f2b(v);
      }
    }
  }
}

// -------------------------------------------------------------- stage 2 -----
__global__ void stage2_kernel(const bf16* __restrict__ Tm, const bf16* __restrict__ Td,
                              const int* __restrict__ central_m, const int* __restrict__ central_d,
                              bf16* __restrict__ BXm, bf16* __restrict__ BXd)
{
  const int idx = blockIdx.x*blockDim.x + threadIdx.x;   // [0, 2*256*4096)
  const int oside = idx >> 20;
  const int rem = idx & 1048575;
  const int n = rem >> 12;
  const int c = rem & 4095;
  const bf16* T = oside ? Tm : Td;                 // source feats = opposite side
  const int* cen = oside ? central_m : central_d;  // column centrality = source side
  bf16* B = oside ? BXd : BXm;
  const bool cc = cen[c] != 0;
  int v0i, v1i;
  if (!oside){ v0i = cc ? 2 : 3; v1i = cc ? 0 : 1; }   // md: V0 = S34/S67, V1 = S01/S25
  else       { v0i = cc ? 1 : 3; v1i = cc ? 0 : 2; }   // dm: V0 = S25/S67, V1 = S01/S34
  const float v0 = b2f(T[(size_t)v0i*1048576 + (size_t)n*4096 + c]);
  const float v1 = b2f(T[(size_t)v1i*1048576 + (size_t)n*4096 + c]);
  B[(size_t)n*4096 + c]         = f2b(v0);
  B[(size_t)(256+n)*4096 + c]   = f2b(v1 - v0);
}

// -------------------------------------------------------------- colsum ------
__global__ void colsum_kernel(const bf16* __restrict__ BHm, const bf16* __restrict__ BHd,
                              float* __restrict__ Scol)
{
  const int b = blockIdx.x;          // [0,512)
  const int sd = b >> 8, n = b & 255;
  const int lane = threadIdx.x;      // 64
  const bf16* rowp = (sd ? BHd : BHm) + (size_t)(256+n)*4096;
  float s = 0.f;
  #pragma unroll
  for (int t=0;t<8;t++){
    const uint4 v = *(const uint4*)(rowp + t*512 + lane*8);
    unsigned short u[8]; __builtin_memcpy(u,&v,16);
    #pragma unroll
    for (int jj=0;jj<8;jj++) s += rawb2f(u[jj]);
  }
  #pragma unroll
  for (int off=32; off>0; off>>=1) s += __shfl_down(s, off);
  if (lane==0) Scol[sd*256 + n] = s;
}

// ---------------------------------------------------------------- zero ------
__global__ void zero_kernel(float* __restrict__ p)
{
  const size_t idx = (size_t)blockIdx.x*blockDim.x + threadIdx.x;   // [0, 262144)
  float4 z = {0.f,0.f,0.f,0.f};
  #pragma unroll
  for (int t=0;t<4;t++) *(float4*)(p + (idx + (size_t)t*262144)*4) = z;
}

// ------------------------------------------------------------ main GEMM -----
// v4: 512 blocks x 512 threads. Swizzled work id w: seg(4-bit-K-split) x
// mt(32) x p(4); each block computes output rows [mt*128,+128) x ALL 256 cols
// for problem p over K segment seg -> A fp32 read exactly once.
// Per kt (BK=32): stage(kt+1) into buf^1 (async B, reg->cvt->LDS A) is issued
// BEFORE compute(kt) on buf; single __syncthreads per kt = pipeline boundary.
__global__ __launch_bounds__(512,2) void gemm_kernel(
    const float* __restrict__ bigraph, const float* __restrict__ m_co, const float* __restrict__ d_co,
    const int* __restrict__ central_m, const int* __restrict__ central_d,
    const float* __restrict__ scal,
    const bf16* __restrict__ BHm, const bf16* __restrict__ BHd,
    const bf16* __restrict__ BXm, const bf16* __restrict__ BXd,
    float* __restrict__ partial)
{
  __shared__ __align__(16) bf16 As[2][128*32];   // 2 x 8 KB
  __shared__ __align__(16) bf16 Bs[2][512*32];   // 2 x 32 KB  (group0 rows 0-255, group1 rows 256-511)
  const int bid = blockIdx.x;
  // bijective XCD swizzle (512 % 8 == 0): XCD k gets w in [k*64, k*64+64)
  const int w = (bid & 7)*64 + (bid >> 3);
  const int seg = w & 3, mt = (w >> 2) & 31, p = w >> 7;
  const int s = p & 1;
  const bool maskmode = (p < 2);
  const int k0 = seg*1024;
  const int rowbase = mt*128;
  const float* Asrc; int apitch; int acoff;
  if (p==0){ Asrc = m_co; apitch = 4096; acoff = 0; }
  else if (p==1){ Asrc = d_co; apitch = 4096; acoff = 0; }
  else if (p==2){ Asrc = bigraph; apitch = 8192; acoff = 4096; }
  else { Asrc = bigraph + (size_t)4096*8192; apitch = 8192; acoff = 0; }
  const bf16* B0 = (p==0) ? BHm : (p==1) ? BHd : (p==2) ? BXm : BXd;

  const int tid = threadIdx.x;
  const int lane = tid&63, wv = tid>>6;           // 8 waves
  const int wr = wv>>2, wc = wv&3;                // 2 x 4 wave grid
  const int q = lane>>4, l15 = lane&15;

  floatx4 acc0[4][4], acc1[4][4];
  #pragma unroll
  for (int i=0;i<4;i++)
    #pragma unroll
    for (int j=0;j<4;j++)
      #pragma unroll
      for (int r=0;r<4;r++){ acc0[i][j][r] = 0.f; acc1[i][j][r] = 0.f; }

  // stage K-tile kt into LDS buffer buf. B: async 16B chunks, source col-group
  // pre-swizzled (inverse of read swizzle). A: fp32 load -> bf16 (mask applied
  // for p<2) -> linear ds_write at the swizzled slot's source.
  auto stage = [&](int kt, int buf){
    const int kkg = k0 + kt*32;
    // ---- B: 2048 chunks of 8 bf16; 4 per thread, wave-uniform LDS base
    #pragma unroll
    for (int j=0;j<4;j++){
      const int cb = wv*256 + j*64;               // wave-uniform chunk base
      const int chunk = cb + lane;
      const int row = chunk>>2, sg = chunk&3;
      const int gg = sg ^ ((row>>1)&3);
      const bf16* gp = B0 + (size_t)row*4096 + kkg + gg*8;
      async_ld16(gp, &Bs[buf][cb*8]);
    }
    // ---- A: 512 chunks of 8 bf16; 1 per thread
    {
      const int chunk = tid;
      const int row = chunk>>2, sg = chunk&3;
      const int g = sg ^ ((row>>1)&3);
      const int gr = rowbase + row;
      const float* ap = Asrc + (size_t)gr*apitch + acoff + kkg + g*8;
      float4 a0 = *(const float4*)ap, a1 = *(const float4*)(ap+4);
      const float av[8] = {a0.x,a0.y,a0.z,a0.w,a1.x,a1.y,a1.z,a1.w};
      unsigned short u[8];
      if (maskmode){
        const int cbase = kkg + g*8;
        #pragma unroll
        for (int jj=0;jj<8;jj++)
          u[jj] = (av[jj]!=0.0f && (cbase+jj)!=gr) ? (unsigned short)0x3F80 : (unsigned short)0;
      } else {
        #pragma unroll
        for (int jj=0;jj<8;jj++) u[jj] = f2bu(av[jj]);
      }
      uint4 w4; __builtin_memcpy(&w4,u,16);
      *(uint4*)(&As[buf][chunk*8]) = w4;
    }
  };

  stage(0, 0);
  __syncthreads();

  for (int kt=0; kt<32; kt++){
    const int cur = kt & 1;
    if (kt+1 < 32) stage(kt+1, cur^1);            // overlaps compute below
    // ---- compute on buf[cur]
    bf16x8 af[4];
    #pragma unroll
    for (int i=0;i<4;i++){
      const int ra = wr*64 + i*16 + l15;
      af[i] = *(const bf16x8*)&As[cur][ra*32 + ((q ^ ((ra>>1)&3)))*8];
    }
    #pragma unroll
    for (int j=0;j<4;j++){
      const int rb = wc*64 + j*16 + l15;
      const int off = rb*32 + ((q ^ ((rb>>1)&3)))*8;
      const bf16x8 b0 = *(const bf16x8*)&Bs[cur][off];
      const bf16x8 b1 = *(const bf16x8*)&Bs[cur][256*32 + off];
      #pragma unroll
      for (int i=0;i<4;i++){
        acc0[i][j] = __builtin_amdgcn_mfma_f32_16x16x32_bf16(af[i], b0, acc0[i][j], 0,0,0);
        acc1[i][j] = __builtin_amdgcn_mfma_f32_16x16x32_bf16(af[i], b1, acc1[i][j], 0,0,0);
      }
    }
    __syncthreads();                               // drains async B + makes As[cur^1] visible
  }

  // ---- epilogue: combine groups with row scales, atomicAdd into partial[p]
  const float* scS = scal + (size_t)s*12288;
  const int* cenR = s ? central_d : central_m;
  float* pb = partial + (size_t)p*4096*256;
  #pragma unroll
  for (int i=0;i<4;i++){
    #pragma unroll
    for (int r_=0;r_<4;r_++){
      const int rl = rowbase + wr*64 + i*16 + q*4 + r_;
      float w0, w1;
      if (maskmode){ w0 = scS[rl]; w1 = -scS[4096+rl]; }
      else { const float nr = scS[8192+rl]; w0 = nr; w1 = cenR[rl] ? nr : 0.f; }
      #pragma unroll
      for (int j=0;j<4;j++){
        const int gcol = wc*64 + j*16 + l15;
        atomicAdd(&pb[(size_t)rl*256 + gcol], w0*acc0[i][j][r_] + w1*acc1[i][j][r_]);
      }
    }
  }
}

// -------------------------------------------------------------- reduce ------
__global__ void reduce_kernel(const float* __restrict__ partial,
                              const float* __restrict__ L0m, const float* __restrict__ L0d,
                              const float* __restrict__ L2nm, const float* __restrict__ L2nd,
                              const float* __restrict__ Scol, const float* __restrict__ scal,
                              float* __restrict__ out)
{
  const int idx = blockIdx.x*blockDim.x + threadIdx.x;   // [0, 524288)
  const int r = idx >> 6;
  const int n4 = (idx & 63) << 2;
  const int s = r >> 12;            // 0: m, 1: d
  const int rl = r & 4095;
  const float r1 = scal[s*12288 + 4096 + rl];
  const size_t rb = (size_t)rl*256 + n4;
  const float4 l0 = *(const float4*)((s? L0d : L0m) + rb);
  const float4 l2 = *(const float4*)((s? L2nd : L2nm) + rb);
  const float4 sc = *(const float4*)(Scol + s*256 + n4);
  const float4 ph = *(const float4*)(partial + (size_t)s*1048576 + rb);
  const float4 px = *(const float4*)(partial + (size_t)(2+s)*1048576 + rb);
  const float r1sq = r1*r1;
  float4 o;
  o.x = l0.x + ph.x + px.x + r1*sc.x - r1sq*l2.x;
  o.y = l0.y + ph.y + px.y + r1*sc.y - r1sq*l2.y;
  o.z = l0.z + ph.z + px.z + r1*sc.z - r1sq*l2.z;
  o.w = l0.w + ph.w + px.w + r1*sc.w - r1sq*l2.w;
  *(float4*)(out + (size_t)r*256 + n4) = o;
}

// ---------------------------------------------------------------------------
extern "C" void kernel_launch(void* const* d_in, const int* in_sizes, int n_in,
                              void* d_out, int out_size, void* d_ws, size_t ws_size,
                              hipStream_t stream)
{
  (void)in_sizes; (void)n_in; (void)out_size; (void)ws_size;
  const float* m_d_feat   = (const float*)d_in[0];
  const float* bigraph    = (const float*)d_in[1];
  const float* m_co       = (const float*)d_in[2];
  const float* d_co       = (const float*)d_in[3];
  const float* m_co_deg   = (const float*)d_in[4];
  const float* d_co_deg   = (const float*)d_in[5];
  const float* m_d_degree = (const float*)d_in[6];
  const float* d_m_degree = (const float*)d_in[7];
  const float* Wm = (const float*)d_in[8];
  const float* bm = (const float*)d_in[9];
  const float* Wd = (const float*)d_in[10];
  const float* bd = (const float*)d_in[11];
  const float* Wx = (const float*)d_in[12];
  const float* bx = (const float*)d_in[13];
  const int* central_m = (const int*)d_in[14];
  const int* central_d = (const int*)d_in[15];

  char* ws = (char*)d_ws;
  bf16*  BHm  = (bf16*) (ws + 0);          // [512][4096] bf16 = 4 MB
  bf16*  BHd  = (bf16*) (ws + 4194304);
  bf16*  BXm  = (bf16*) (ws + 8388608);
  bf16*  BXd  = (bf16*) (ws + 12582912);
  float* L0m  = (float*)(ws + 16777216);   // [4096][256] fp32 = 4 MB
  float* L0d  = (float*)(ws + 20971520);
  float* L2nm = (float*)(ws + 25165824);
  float* L2nd = (float*)(ws + 29360128);
  float* Sbuf = (float*)(ws + 33554432);   // 1 MB
  float* bSbuf= (float*)(ws + 34603008);   // 4 KB
  float* scal = (float*)(ws + 34607104);   // 96 KB
  float* Scol = (float*)(ws + 34705408);   // 2 KB
  bf16*  Tm   = (bf16*) (ws + 34707456);   // 8 MB
  bf16*  Td   = (bf16*) (ws + 43096064);   // 8 MB (end 51,484,672)
  float* partial = (float*)(ws + 34707456); // 16 MB, ALIASES Tm/Td (dead after stage2)

  prep_kernel<<<256, 256, 0, stream>>>(m_co_deg, d_co_deg, m_d_degree, d_m_degree,
                                       Wx, bx, scal, Sbuf, bSbuf);
  stage1_kernel<<<dim3(64,16), 256, 0, stream>>>(m_d_feat, Wm, bm, Wd, bd, Sbuf, bSbuf, scal,
                                                 BHm, BHd, L0m, L0d, L2nm, L2nd, Tm, Td);
  stage2_kernel<<<8192, 256, 0, stream>>>(Tm, Td, central_m, central_d, BXm, BXd);
  colsum_kernel<<<512, 64, 0, stream>>>(BHm, BHd, Scol);
  zero_kernel<<<1024, 256, 0, stream>>>(partial);
  gemm_kernel<<<512, 512, 0, stream>>>(bigraph, m_co, d_co, central_m, central_d,
                                       scal, BHm, BHd, BXm, BXd, partial);
  reduce_kernel<<<2048, 256, 0, stream>>>(partial, L0m, L0d, L2nm, L2nd, Scol, scal, (float*)d_out);
}

// Round 3
// 602.478 us; speedup vs baseline: 1.0157x; 1.0157x over previous
//
#include <hip/hip_runtime.h>
#include <hip/hip_bf16.h>

// R-GCN v5.1: fix gemm vmcnt-ordering poison (T14 async-STAGE split).
// v4 post-mortem: per-kt cost 7.1K cyc vs ~375 cyc floor — stage() issued A
// fp32 loads AFTER the async B global_load_lds ops, so the A ds_write forced
// vmcnt(0) (draining the B asyncs too) BEFORE compute: every kt serialized a
// full HBM round trip. v5 schedule per kt:
//   top:    issue A loads (oldest) + B asyncs for kt+1   [sched_barrier pin]
//   middle: compute(kt) — pure LDS + MFMA, no vmem waits [sched_barrier pin]
//   bottom: vmcnt(8)-wait A regs only -> cvt -> ds_write As[nxt]
//   barrier: vmcnt(0) drain of B now hidden under compute+writeA
// A loads nontemporal (streamed once; keep L2 for B panels).
// v5.1: __builtin_nontemporal_load needs a clang ext_vector_type, not HIP's
// float4 class -> use f32x4 alias for the A loads.

typedef __bf16 bf16x8 __attribute__((ext_vector_type(8)));
typedef float floatx4 __attribute__((ext_vector_type(4)));
typedef float f32x4 __attribute__((ext_vector_type(4)));
using bf16 = __hip_bfloat16;

#define LDK 72   // stage1 LDS pad

__device__ __forceinline__ float b2f(bf16 x){ return __bfloat162float(x); }
__device__ __forceinline__ bf16 f2b(float f){ return __float2bfloat16(f); }
__device__ __forceinline__ float rawb2f(unsigned short u){
  unsigned int x = ((unsigned int)u) << 16; float f; __builtin_memcpy(&f,&x,4); return f;
}
__device__ __forceinline__ unsigned short f2bu(float f){
  bf16 h = __float2bfloat16(f); unsigned short u; __builtin_memcpy(&u,&h,2); return u;
}
__device__ __forceinline__ uint4 cvt8(float4 a, float4 b){
  unsigned short u[8] = {f2bu(a.x),f2bu(a.y),f2bu(a.z),f2bu(a.w),
                         f2bu(b.x),f2bu(b.y),f2bu(b.z),f2bu(b.w)};
  uint4 v; __builtin_memcpy(&v,u,16); return v;
}
// async global->LDS, 16B per lane; lds dest = wave-uniform base + lane*16
__device__ __forceinline__ void async_ld16(const void* gp, void* lp){
  typedef __attribute__((address_space(1))) const unsigned int GU;
  typedef __attribute__((address_space(3))) unsigned int LU;
  __builtin_amdgcn_global_load_lds((GU*)(unsigned long long)gp,
                                   (LU*)(unsigned int)(unsigned long long)lp,
                                   16, 0, 0);
}

// ---------------------------------------------------------------- prep ------
__global__ void prep_kernel(const float* __restrict__ m_co_deg, const float* __restrict__ d_co_deg,
                            const float* __restrict__ m_d_degree, const float* __restrict__ d_m_degree,
                            const float* __restrict__ Wx, const float* __restrict__ bx,
                            float* __restrict__ scal, float* __restrict__ Sbuf, float* __restrict__ bSbuf)
{
  const int i = blockIdx.x*blockDim.x + threadIdx.x;
  if (i < 4096){
    scal[0*4096+i] = rsqrtf(m_co_deg[2*i]);
    scal[1*4096+i] = rsqrtf(m_co_deg[2*i+1]);
    scal[2*4096+i] = 0.5f / m_d_degree[i];
    scal[3*4096+i] = rsqrtf(d_co_deg[2*i]);
    scal[4*4096+i] = rsqrtf(d_co_deg[2*i+1]);
    scal[5*4096+i] = 0.5f / d_m_degree[i];
  }
  const int pa[4] = {0,2,3,6}, pb[4] = {1,5,4,7};
  if (i < 65536){
    #pragma unroll
    for (int s=0;s<4;s++)
      Sbuf[s*65536+i] = Wx[pa[s]*65536+i] + Wx[pb[s]*65536+i];
  }
  if (i < 256){
    #pragma unroll
    for (int s=0;s<4;s++)
      bSbuf[s*256+i] = bx[pa[s]*256+i] + bx[pb[s]*256+i];
  }
}

// -------------------------------------------------------------- stage 1 -----
__global__ __launch_bounds__(256) void stage1_kernel(
    const float* __restrict__ feat, const float* __restrict__ Wm, const float* __restrict__ bm,
    const float* __restrict__ Wd, const float* __restrict__ bd,
    const float* __restrict__ Sbuf, const float* __restrict__ bSbuf, const float* __restrict__ scal,
    bf16* __restrict__ BHm, bf16* __restrict__ BHd,
    float* __restrict__ L0m, float* __restrict__ L0d,
    float* __restrict__ L2nm, float* __restrict__ L2nd,
    bf16* __restrict__ Tm, bf16* __restrict__ Td)
{
  __shared__ __align__(16) bf16 As[128*LDK];
  __shared__ __align__(16) bf16 Bs[128*LDK];
  const int p = blockIdx.y;
  const int side = p >> 3, widx = p & 7;
  const int bx_ = blockIdx.x;
  const bool modeT = (widx != 0 && widx != 7);
  const float* X = feat + (size_t)side*(4096*256);
  const float* Wb = side ? Wd : Wm;
  const float* W = (widx==0) ? Wb : (widx==7) ? (Wb + 2*65536)
                 : (widx<=2) ? (Wb + widx*65536) : (Sbuf + (widx-3)*65536);
  int rt, ct;
  if (!modeT){ rt = bx_>>1; ct = bx_&1; } else { rt = bx_&1; ct = bx_>>1; }
  const float* Amat = modeT ? W : X;
  const float* Bmat = modeT ? X : W;
  const int arow0 = rt*128, brow0 = ct*128;
  const int tid = threadIdx.x;
  const int lane = tid & 63, wv = tid>>6;
  const int wr = wv>>1, wc = wv&1, q = lane>>4, l15 = lane&15;

  floatx4 acc[4][4];
  #pragma unroll
  for (int i=0;i<4;i++)
    #pragma unroll
    for (int j=0;j<4;j++)
      #pragma unroll
      for (int r=0;r<4;r++) acc[i][j][r] = 0.f;

  for (int kt=0; kt<4; kt++){
    const int c0 = kt*64;
    __syncthreads();
    #pragma unroll
    for (int i=0;i<4;i++){
      const int id = tid + i*256;
      const int row = id>>3, kg = id&7;
      const float* ap = Amat + (size_t)(arow0+row)*256 + c0 + kg*8;
      const float* bp = Bmat + (size_t)(brow0+row)*256 + c0 + kg*8;
      float4 a0 = *(const float4*)ap, a1 = *(const float4*)(ap+4);
      float4 b0 = *(const float4*)bp, b1 = *(const float4*)(bp+4);
      *(uint4*)(&As[row*LDK + kg*8]) = cvt8(a0,a1);
      *(uint4*)(&Bs[row*LDK + kg*8]) = cvt8(b0,b1);
    }
    __syncthreads();
    #pragma unroll
    for (int ki=0; ki<2; ki++){
      bf16x8 af[4], bg[4];
      #pragma unroll
      for (int i=0;i<4;i++) af[i] = *(const bf16x8*)&As[(wr*64 + i*16 + l15)*LDK + ki*32 + q*8];
      #pragma unroll
      for (int j=0;j<4;j++) bg[j] = *(const bf16x8*)&Bs[(wc*64 + j*16 + l15)*LDK + ki*32 + q*8];
      #pragma unroll
      for (int i=0;i<4;i++)
        #pragma unroll
        for (int j=0;j<4;j++)
          acc[i][j] = __builtin_amdgcn_mfma_f32_16x16x32_bf16(af[i], bg[j], acc[i][j], 0,0,0);
    }
  }

  const float* bb = side ? bd : bm;
  const float* bias = (widx==0) ? bb : (widx==7) ? (bb + 512)
                    : (widx<=2) ? (bb + widx*256) : (bSbuf + (widx-3)*256);
  float* outF = nullptr; bf16* outB = nullptr; int pitch = 256; const float* scl = nullptr;
  if (widx==0){ outF = side? L0d : L0m; }
  else if (widx==7){ outF = side? L2nd : L2nm; }
  else if (widx==1){ outB = side? BHd : BHm; pitch = 4096; scl = scal + side*12288; }
  else if (widx==2){ outB = (side? BHd : BHm) + 256*4096; pitch = 4096; scl = scal + side*12288 + 4096; }
  else { outB = (side? Td : Tm) + (widx-3)*(256*4096); pitch = 4096; }

  #pragma unroll
  for (int i=0;i<4;i++){
    #pragma unroll
    for (int j=0;j<4;j++){
      const int gcol = brow0 + wc*64 + j*16 + l15;
      #pragma unroll
      for (int r=0;r<4;r++){
        const int grow = arow0 + wr*64 + i*16 + q*4 + r;
        float v = acc[i][j][r];
        const int nidx = modeT ? grow : gcol;
        v += bias[nidx];
        if (scl) v *= scl[gcol];
        if (outF) outF[(size_t)grow*pitch + gcol] = v;
        else      outB[(size_t)grow*pitch + gcol] = f2b(v);
      }
    }
  }
}

// -------------------------------------------------------------- stage 2 -----
__global__ void stage2_kernel(const bf16* __restrict__ Tm, const bf16* __restrict__ Td,
                              const int* __restrict__ central_m, const int* __restrict__ central_d,
                              bf16* __restrict__ BXm, bf16* __restrict__ BXd)
{
  const int idx = blockIdx.x*blockDim.x + threadIdx.x;   // [0, 2*256*4096)
  const int oside = idx >> 20;
  const int rem = idx & 1048575;
  const int n = rem >> 12;
  const int c = rem & 4095;
  const bf16* T = oside ? Tm : Td;                 // source feats = opposite side
  const int* cen = oside ? central_m : central_d;  // column centrality = source side
  bf16* B = oside ? BXd : BXm;
  const bool cc = cen[c] != 0;
  int v0i, v1i;
  if (!oside){ v0i = cc ? 2 : 3; v1i = cc ? 0 : 1; }   // md: V0 = S34/S67, V1 = S01/S25
  else       { v0i = cc ? 1 : 3; v1i = cc ? 0 : 2; }   // dm: V0 = S25/S67, V1 = S01/S34
  const float v0 = b2f(T[(size_t)v0i*1048576 + (size_t)n*4096 + c]);
  const float v1 = b2f(T[(size_t)v1i*1048576 + (size_t)n*4096 + c]);
  B[(size_t)n*4096 + c]         = f2b(v0);
  B[(size_t)(256+n)*4096 + c]   = f2b(v1 - v0);
}

// -------------------------------------------------------------- colsum ------
__global__ void colsum_kernel(const bf16* __restrict__ BHm, const bf16* __restrict__ BHd,
                              float* __restrict__ Scol)
{
  const int b = blockIdx.x;          // [0,512)
  const int sd = b >> 8, n = b & 255;
  const int lane = threadIdx.x;      // 64
  const bf16* rowp = (sd ? BHd : BHm) + (size_t)(256+n)*4096;
  float s = 0.f;
  #pragma unroll
  for (int t=0;t<8;t++){
    const uint4 v = *(const uint4*)(rowp + t*512 + lane*8);
    unsigned short u[8]; __builtin_memcpy(u,&v,16);
    #pragma unroll
    for (int jj=0;jj<8;jj++) s += rawb2f(u[jj]);
  }
  #pragma unroll
  for (int off=32; off>0; off>>=1) s += __shfl_down(s, off);
  if (lane==0) Scol[sd*256 + n] = s;
}

// ---------------------------------------------------------------- zero ------
__global__ void zero_kernel(float* __restrict__ p)
{
  const size_t idx = (size_t)blockIdx.x*blockDim.x + threadIdx.x;   // [0, 262144)
  float4 z = {0.f,0.f,0.f,0.f};
  #pragma unroll
  for (int t=0;t<4;t++) *(float4*)(p + (idx + (size_t)t*262144)*4) = z;
}

// ------------------------------------------------------------ main GEMM -----
// v5: 512 blocks x 512 threads, BK=32, double-buffered LDS (80 KB).
// Per kt: {issue A loads + B asyncs for kt+1} -> compute(kt) -> {vmcnt-wait A
// only, cvt, ds_write} -> __syncthreads. A-latency hides under compute;
// B-async drain at the barrier hides under compute+writeA.
__global__ __launch_bounds__(512,2) void gemm_kernel(
    const float* __restrict__ bigraph, const float* __restrict__ m_co, const float* __restrict__ d_co,
    const int* __restrict__ central_m, const int* __restrict__ central_d,
    const float* __restrict__ scal,
    const bf16* __restrict__ BHm, const bf16* __restrict__ BHd,
    const bf16* __restrict__ BXm, const bf16* __restrict__ BXd,
    float* __restrict__ partial)
{
  __shared__ __align__(16) bf16 As[2][128*32];   // 2 x 8 KB
  __shared__ __align__(16) bf16 Bs[2][512*32];   // 2 x 32 KB
  const int bid = blockIdx.x;
  // bijective XCD swizzle (512 % 8 == 0)
  const int w = (bid & 7)*64 + (bid >> 3);
  const int seg = w & 3, mt = (w >> 2) & 31, p = w >> 7;
  const int s = p & 1;
  const bool maskmode = (p < 2);
  const int k0 = seg*1024;
  const int rowbase = mt*128;
  const float* Asrc; int apitch; int acoff;
  if (p==0){ Asrc = m_co; apitch = 4096; acoff = 0; }
  else if (p==1){ Asrc = d_co; apitch = 4096; acoff = 0; }
  else if (p==2){ Asrc = bigraph; apitch = 8192; acoff = 4096; }
  else { Asrc = bigraph + (size_t)4096*8192; apitch = 8192; acoff = 0; }
  const bf16* B0 = (p==0) ? BHm : (p==1) ? BHd : (p==2) ? BXm : BXd;

  const int tid = threadIdx.x;
  const int lane = tid&63, wv = tid>>6;           // 8 waves
  const int wr = wv>>2, wc = wv&3;                // 2 x 4 wave grid
  const int q = lane>>4, l15 = lane&15;

  // ---- kt-invariant staging geometry (hoisted)
  // A: one 16B chunk per thread
  const int a_row = tid>>2, a_sg = tid&3;
  const int a_g  = a_sg ^ ((a_row>>1)&3);
  const int a_gr = rowbase + a_row;
  const float* a_base = Asrc + (size_t)a_gr*apitch + acoff + a_g*8;  // + kkg per kt
  // B: four async chunks per thread (row/swizzle fixed; col varies with kt)
  int b_roff[4]; int b_ldsoff[4];
  #pragma unroll
  for (int j=0;j<4;j++){
    const int cb = wv*256 + j*64;                 // wave-uniform chunk base
    const int chunk = cb + lane;
    const int row = chunk>>2, sg = chunk&3;
    const int gg = sg ^ ((row>>1)&3);
    b_roff[j] = row*4096 + gg*8;
    b_ldsoff[j] = cb*8;
  }

  floatx4 acc0[4][4], acc1[4][4];
  #pragma unroll
  for (int i=0;i<4;i++)
    #pragma unroll
    for (int j=0;j<4;j++)
      #pragma unroll
      for (int r=0;r<4;r++){ acc0[i][j][r] = 0.f; acc1[i][j][r] = 0.f; }

  // ---- helpers
  auto issueB = [&](int kkg, int buf){
    #pragma unroll
    for (int j=0;j<4;j++)
      async_ld16(B0 + (size_t)b_roff[j] + kkg, &Bs[buf][b_ldsoff[j]]);
  };
  auto writeA = [&](f32x4 a0, f32x4 a1, int kkg, int buf){
    const float av[8] = {a0[0],a0[1],a0[2],a0[3],a1[0],a1[1],a1[2],a1[3]};
    unsigned short u[8];
    if (maskmode){
      const int cbase = kkg + a_g*8;
      #pragma unroll
      for (int jj=0;jj<8;jj++)
        u[jj] = (av[jj]!=0.0f && (cbase+jj)!=a_gr) ? (unsigned short)0x3F80 : (unsigned short)0;
    } else {
      #pragma unroll
      for (int jj=0;jj<8;jj++) u[jj] = f2bu(av[jj]);
    }
    uint4 w4; __builtin_memcpy(&w4,u,16);
    *(uint4*)(&As[buf][tid*8]) = w4;
  };

  // ---- prologue: stage kt=0 into buf 0
  {
    const int kkg = k0;
    const float* ap = a_base + kkg;
    f32x4 a0 = __builtin_nontemporal_load((const f32x4*)ap);
    f32x4 a1 = __builtin_nontemporal_load((const f32x4*)(ap+4));
    issueB(kkg, 0);
    writeA(a0, a1, kkg, 0);
  }
  __syncthreads();

  for (int kt=0; kt<32; kt++){
    const int cur = kt & 1;
    const bool pre = (kt+1 < 32);
    f32x4 a0, a1;
    const int nkkg = k0 + (kt+1)*32;
    if (pre){
      // A loads issued FIRST (oldest in vmcnt queue), then B asyncs:
      // the later vmcnt wait for A leaves B in flight.
      const float* ap = a_base + nkkg;
      a0 = __builtin_nontemporal_load((const f32x4*)ap);
      a1 = __builtin_nontemporal_load((const f32x4*)(ap+4));
      issueB(nkkg, cur^1);
    }
    __builtin_amdgcn_sched_barrier(0);   // pin load-issue above compute

    // ---- compute on buf[cur] (pure LDS + MFMA)
    bf16x8 af[4];
    #pragma unroll
    for (int i=0;i<4;i++){
      const int ra = wr*64 + i*16 + l15;
      af[i] = *(const bf16x8*)&As[cur][ra*32 + ((q ^ ((ra>>1)&3)))*8];
    }
    #pragma unroll
    for (int j=0;j<4;j++){
      const int rb = wc*64 + j*16 + l15;
      const int off = rb*32 + ((q ^ ((rb>>1)&3)))*8;
      const bf16x8 b0 = *(const bf16x8*)&Bs[cur][off];
      const bf16x8 b1 = *(const bf16x8*)&Bs[cur][256*32 + off];
      #pragma unroll
      for (int i=0;i<4;i++){
        acc0[i][j] = __builtin_amdgcn_mfma_f32_16x16x32_bf16(af[i], b0, acc0[i][j], 0,0,0);
        acc1[i][j] = __builtin_amdgcn_mfma_f32_16x16x32_bf16(af[i], b1, acc1[i][j], 0,0,0);
      }
    }
    __builtin_amdgcn_sched_barrier(0);   // pin A-wait/cvt/ds_write below compute

    if (pre) writeA(a0, a1, nkkg, cur^1);   // vmcnt wait covers A only
    __syncthreads();                        // drains B asyncs (hidden above)
  }

  // ---- epilogue: combine groups with row scales, atomicAdd into partial[p]
  const float* scS = scal + (size_t)s*12288;
  const int* cenR = s ? central_d : central_m;
  float* pb = partial + (size_t)p*4096*256;
  #pragma unroll
  for (int i=0;i<4;i++){
    #pragma unroll
    for (int r_=0;r_<4;r_++){
      const int rl = rowbase + wr*64 + i*16 + q*4 + r_;
      float w0, w1;
      if (maskmode){ w0 = scS[rl]; w1 = -scS[4096+rl]; }
      else { const float nr = scS[8192+rl]; w0 = nr; w1 = cenR[rl] ? nr : 0.f; }
      #pragma unroll
      for (int j=0;j<4;j++){
        const int gcol = wc*64 + j*16 + l15;
        atomicAdd(&pb[(size_t)rl*256 + gcol], w0*acc0[i][j][r_] + w1*acc1[i][j][r_]);
      }
    }
  }
}

// -------------------------------------------------------------- reduce ------
__global__ void reduce_kernel(const float* __restrict__ partial,
                              const float* __restrict__ L0m, const float* __restrict__ L0d,
                              const float* __restrict__ L2nm, const float* __restrict__ L2nd,
                              const float* __restrict__ Scol, const float* __restrict__ scal,
                              float* __restrict__ out)
{
  const int idx = blockIdx.x*blockDim.x + threadIdx.x;   // [0, 524288)
  const int r = idx >> 6;
  const int n4 = (idx & 63) << 2;
  const int s = r >> 12;            // 0: m, 1: d
  const int rl = r & 4095;
  const float r1 = scal[s*12288 + 4096 + rl];
  const size_t rb = (size_t)rl*256 + n4;
  const float4 l0 = *(const float4*)((s? L0d : L0m) + rb);
  const float4 l2 = *(const float4*)((s? L2nd : L2nm) + rb);
  const float4 sc = *(const float4*)(Scol + s*256 + n4);
  const float4 ph = *(const float4*)(partial + (size_t)s*1048576 + rb);
  const float4 px = *(const float4*)(partial + (size_t)(2+s)*1048576 + rb);
  const float r1sq = r1*r1;
  float4 o;
  o.x = l0.x + ph.x + px.x + r1*sc.x - r1sq*l2.x;
  o.y = l0.y + ph.y + px.y + r1*sc.y - r1sq*l2.y;
  o.z = l0.z + ph.z + px.z + r1*sc.z - r1sq*l2.z;
  o.w = l0.w + ph.w + px.w + r1*sc.w - r1sq*l2.w;
  *(float4*)(out + (size_t)r*256 + n4) = o;
}

// ---------------------------------------------------------------------------
extern "C" void kernel_launch(void* const* d_in, const int* in_sizes, int n_in,
                              void* d_out, int out_size, void* d_ws, size_t ws_size,
                              hipStream_t stream)
{
  (void)in_sizes; (void)n_in; (void)out_size; (void)ws_size;
  const float* m_d_feat   = (const float*)d_in[0];
  const float* bigraph    = (const float*)d_in[1];
  const float* m_co       = (const float*)d_in[2];
  const float* d_co       = (const float*)d_in[3];
  const float* m_co_deg   = (const float*)d_in[4];
  const float* d_co_deg   = (const float*)d_in[5];
  const float* m_d_degree = (const float*)d_in[6];
  const float* d_m_degree = (const float*)d_in[7];
  const float* Wm = (const float*)d_in[8];
  const float* bm = (const float*)d_in[9];
  const float* Wd = (const float*)d_in[10];
  const float* bd = (const float*)d_in[11];
  const float* Wx = (const float*)d_in[12];
  const float* bx = (const float*)d_in[13];
  const int* central_m = (const int*)d_in[14];
  const int* central_d = (const int*)d_in[15];

  char* ws = (char*)d_ws;
  bf16*  BHm  = (bf16*) (ws + 0);          // [512][4096] bf16 = 4 MB
  bf16*  BHd  = (bf16*) (ws + 4194304);
  bf16*  BXm  = (bf16*) (ws + 8388608);
  bf16*  BXd  = (bf16*) (ws + 12582912);
  float* L0m  = (float*)(ws + 16777216);   // [4096][256] fp32 = 4 MB
  float* L0d  = (float*)(ws + 20971520);
  float* L2nm = (float*)(ws + 25165824);
  float* L2nd = (float*)(ws + 29360128);
  float* Sbuf = (float*)(ws + 33554432);   // 1 MB
  float* bSbuf= (float*)(ws + 34603008);   // 4 KB
  float* scal = (float*)(ws + 34607104);   // 96 KB
  float* Scol = (float*)(ws + 34705408);   // 2 KB
  bf16*  Tm   = (bf16*) (ws + 34707456);   // 8 MB
  bf16*  Td   = (bf16*) (ws + 43096064);   // 8 MB (end 51,484,672)
  float* partial = (float*)(ws + 34707456); // 16 MB, ALIASES Tm/Td (dead after stage2)

  prep_kernel<<<256, 256, 0, stream>>>(m_co_deg, d_co_deg, m_d_degree, d_m_degree,
                                       Wx, bx, scal, Sbuf, bSbuf);
  stage1_kernel<<<dim3(64,16), 256, 0, stream>>>(m_d_feat, Wm, bm, Wd, bd, Sbuf, bSbuf, scal,
                                                 BHm, BHd, L0m, L0d, L2nm, L2nd, Tm, Td);
  stage2_kernel<<<8192, 256, 0, stream>>>(Tm, Td, central_m, central_d, BXm, BXd);
  colsum_kernel<<<512, 64, 0, stream>>>(BHm, BHd, Scol);
  zero_kernel<<<1024, 256, 0, stream>>>(partial);
  gemm_kernel<<<512, 512, 0, stream>>>(bigraph, m_co, d_co, central_m, central_d,
                                       scal, BHm, BHd, BXm, BXd, partial);
  reduce_kernel<<<2048, 256, 0, stream>>>(partial, L0m, L0d, L2nm, L2nd, Scol, scal, (float*)d_out);
}

// Round 4
// 569.153 us; speedup vs baseline: 1.0752x; 1.0586x over previous
//
#include <hip/hip_runtime.h>
#include <hip/hip_bf16.h>

// R-GCN v6: kill the gemm atomic epilogue.
// v5 post-mortem: pipeline fix moved gemm 190 -> <159 us, but the epilogue's
// 33.5M fp32 atomicAdds (~64 MB RMW through L2 atomic units) were a second,
// equal-size bottleneck. v6:
//  - split-K 4 -> 2: 256 blocks = exactly 1/CU; each (seg,mt,p) block owns a
//    disjoint 128x256 slab of partial[seg][p] -> plain coalesced fp32 stores.
//  - zero_kernel deleted (no accumulation); reduce sums the 2 K-segments.
//  - partial = [2][4][4096][256] f32 = 32 MB (aliases Tm/Td, dead after stage2).
//  - XCD swizzle keeps each p's 64 blocks on XCD pair {2p,2p+1} (B panel 4 MB,
//    L2-resident per XCD).
// Everything else (v5 async-STAGE split schedule, tiles, swizzles, stage1/2,
// colsum, prep): unchanged.

typedef __bf16 bf16x8 __attribute__((ext_vector_type(8)));
typedef float floatx4 __attribute__((ext_vector_type(4)));
typedef float f32x4 __attribute__((ext_vector_type(4)));
using bf16 = __hip_bfloat16;

#define LDK 72   // stage1 LDS pad

__device__ __forceinline__ float b2f(bf16 x){ return __bfloat162float(x); }
__device__ __forceinline__ bf16 f2b(float f){ return __float2bfloat16(f); }
__device__ __forceinline__ float rawb2f(unsigned short u){
  unsigned int x = ((unsigned int)u) << 16; float f; __builtin_memcpy(&f,&x,4); return f;
}
__device__ __forceinline__ unsigned short f2bu(float f){
  bf16 h = __float2bfloat16(f); unsigned short u; __builtin_memcpy(&u,&h,2); return u;
}
__device__ __forceinline__ uint4 cvt8(float4 a, float4 b){
  unsigned short u[8] = {f2bu(a.x),f2bu(a.y),f2bu(a.z),f2bu(a.w),
                         f2bu(b.x),f2bu(b.y),f2bu(b.z),f2bu(b.w)};
  uint4 v; __builtin_memcpy(&v,u,16); return v;
}
// async global->LDS, 16B per lane; lds dest = wave-uniform base + lane*16
__device__ __forceinline__ void async_ld16(const void* gp, void* lp){
  typedef __attribute__((address_space(1))) const unsigned int GU;
  typedef __attribute__((address_space(3))) unsigned int LU;
  __builtin_amdgcn_global_load_lds((GU*)(unsigned long long)gp,
                                   (LU*)(unsigned int)(unsigned long long)lp,
                                   16, 0, 0);
}

// ---------------------------------------------------------------- prep ------
__global__ void prep_kernel(const float* __restrict__ m_co_deg, const float* __restrict__ d_co_deg,
                            const float* __restrict__ m_d_degree, const float* __restrict__ d_m_degree,
                            const float* __restrict__ Wx, const float* __restrict__ bx,
                            float* __restrict__ scal, float* __restrict__ Sbuf, float* __restrict__ bSbuf)
{
  const int i = blockIdx.x*blockDim.x + threadIdx.x;
  if (i < 4096){
    scal[0*4096+i] = rsqrtf(m_co_deg[2*i]);
    scal[1*4096+i] = rsqrtf(m_co_deg[2*i+1]);
    scal[2*4096+i] = 0.5f / m_d_degree[i];
    scal[3*4096+i] = rsqrtf(d_co_deg[2*i]);
    scal[4*4096+i] = rsqrtf(d_co_deg[2*i+1]);
    scal[5*4096+i] = 0.5f / d_m_degree[i];
  }
  const int pa[4] = {0,2,3,6}, pb[4] = {1,5,4,7};
  if (i < 65536){
    #pragma unroll
    for (int s=0;s<4;s++)
      Sbuf[s*65536+i] = Wx[pa[s]*65536+i] + Wx[pb[s]*65536+i];
  }
  if (i < 256){
    #pragma unroll
    for (int s=0;s<4;s++)
      bSbuf[s*256+i] = bx[pa[s]*256+i] + bx[pb[s]*256+i];
  }
}

// -------------------------------------------------------------- stage 1 -----
__global__ __launch_bounds__(256) void stage1_kernel(
    const float* __restrict__ feat, const float* __restrict__ Wm, const float* __restrict__ bm,
    const float* __restrict__ Wd, const float* __restrict__ bd,
    const float* __restrict__ Sbuf, const float* __restrict__ bSbuf, const float* __restrict__ scal,
    bf16* __restrict__ BHm, bf16* __restrict__ BHd,
    float* __restrict__ L0m, float* __restrict__ L0d,
    float* __restrict__ L2nm, float* __restrict__ L2nd,
    bf16* __restrict__ Tm, bf16* __restrict__ Td)
{
  __shared__ __align__(16) bf16 As[128*LDK];
  __shared__ __align__(16) bf16 Bs[128*LDK];
  const int p = blockIdx.y;
  const int side = p >> 3, widx = p & 7;
  const int bx_ = blockIdx.x;
  const bool modeT = (widx != 0 && widx != 7);
  const float* X = feat + (size_t)side*(4096*256);
  const float* Wb = side ? Wd : Wm;
  const float* W = (widx==0) ? Wb : (widx==7) ? (Wb + 2*65536)
                 : (widx<=2) ? (Wb + widx*65536) : (Sbuf + (widx-3)*65536);
  int rt, ct;
  if (!modeT){ rt = bx_>>1; ct = bx_&1; } else { rt = bx_&1; ct = bx_>>1; }
  const float* Amat = modeT ? W : X;
  const float* Bmat = modeT ? X : W;
  const int arow0 = rt*128, brow0 = ct*128;
  const int tid = threadIdx.x;
  const int lane = tid & 63, wv = tid>>6;
  const int wr = wv>>1, wc = wv&1, q = lane>>4, l15 = lane&15;

  floatx4 acc[4][4];
  #pragma unroll
  for (int i=0;i<4;i++)
    #pragma unroll
    for (int j=0;j<4;j++)
      #pragma unroll
      for (int r=0;r<4;r++) acc[i][j][r] = 0.f;

  for (int kt=0; kt<4; kt++){
    const int c0 = kt*64;
    __syncthreads();
    #pragma unroll
    for (int i=0;i<4;i++){
      const int id = tid + i*256;
      const int row = id>>3, kg = id&7;
      const float* ap = Amat + (size_t)(arow0+row)*256 + c0 + kg*8;
      const float* bp = Bmat + (size_t)(brow0+row)*256 + c0 + kg*8;
      float4 a0 = *(const float4*)ap, a1 = *(const float4*)(ap+4);
      float4 b0 = *(const float4*)bp, b1 = *(const float4*)(bp+4);
      *(uint4*)(&As[row*LDK + kg*8]) = cvt8(a0,a1);
      *(uint4*)(&Bs[row*LDK + kg*8]) = cvt8(b0,b1);
    }
    __syncthreads();
    #pragma unroll
    for (int ki=0; ki<2; ki++){
      bf16x8 af[4], bg[4];
      #pragma unroll
      for (int i=0;i<4;i++) af[i] = *(const bf16x8*)&As[(wr*64 + i*16 + l15)*LDK + ki*32 + q*8];
      #pragma unroll
      for (int j=0;j<4;j++) bg[j] = *(const bf16x8*)&Bs[(wc*64 + j*16 + l15)*LDK + ki*32 + q*8];
      #pragma unroll
      for (int i=0;i<4;i++)
        #pragma unroll
        for (int j=0;j<4;j++)
          acc[i][j] = __builtin_amdgcn_mfma_f32_16x16x32_bf16(af[i], bg[j], acc[i][j], 0,0,0);
    }
  }

  const float* bb = side ? bd : bm;
  const float* bias = (widx==0) ? bb : (widx==7) ? (bb + 512)
                    : (widx<=2) ? (bb + widx*256) : (bSbuf + (widx-3)*256);
  float* outF = nullptr; bf16* outB = nullptr; int pitch = 256; const float* scl = nullptr;
  if (widx==0){ outF = side? L0d : L0m; }
  else if (widx==7){ outF = side? L2nd : L2nm; }
  else if (widx==1){ outB = side? BHd : BHm; pitch = 4096; scl = scal + side*12288; }
  else if (widx==2){ outB = (side? BHd : BHm) + 256*4096; pitch = 4096; scl = scal + side*12288 + 4096; }
  else { outB = (side? Td : Tm) + (widx-3)*(256*4096); pitch = 4096; }

  #pragma unroll
  for (int i=0;i<4;i++){
    #pragma unroll
    for (int j=0;j<4;j++){
      const int gcol = brow0 + wc*64 + j*16 + l15;
      #pragma unroll
      for (int r=0;r<4;r++){
        const int grow = arow0 + wr*64 + i*16 + q*4 + r;
        float v = acc[i][j][r];
        const int nidx = modeT ? grow : gcol;
        v += bias[nidx];
        if (scl) v *= scl[gcol];
        if (outF) outF[(size_t)grow*pitch + gcol] = v;
        else      outB[(size_t)grow*pitch + gcol] = f2b(v);
      }
    }
  }
}

// -------------------------------------------------------------- stage 2 -----
__global__ void stage2_kernel(const bf16* __restrict__ Tm, const bf16* __restrict__ Td,
                              const int* __restrict__ central_m, const int* __restrict__ central_d,
                              bf16* __restrict__ BXm, bf16* __restrict__ BXd)
{
  const int idx = blockIdx.x*blockDim.x + threadIdx.x;   // [0, 2*256*4096)
  const int oside = idx >> 20;
  const int rem = idx & 1048575;
  const int n = rem >> 12;
  const int c = rem & 4095;
  const bf16* T = oside ? Tm : Td;                 // source feats = opposite side
  const int* cen = oside ? central_m : central_d;  // column centrality = source side
  bf16* B = oside ? BXd : BXm;
  const bool cc = cen[c] != 0;
  int v0i, v1i;
  if (!oside){ v0i = cc ? 2 : 3; v1i = cc ? 0 : 1; }   // md: V0 = S34/S67, V1 = S01/S25
  else       { v0i = cc ? 1 : 3; v1i = cc ? 0 : 2; }   // dm: V0 = S25/S67, V1 = S01/S34
  const float v0 = b2f(T[(size_t)v0i*1048576 + (size_t)n*4096 + c]);
  const float v1 = b2f(T[(size_t)v1i*1048576 + (size_t)n*4096 + c]);
  B[(size_t)n*4096 + c]         = f2b(v0);
  B[(size_t)(256+n)*4096 + c]   = f2b(v1 - v0);
}

// -------------------------------------------------------------- colsum ------
__global__ void colsum_kernel(const bf16* __restrict__ BHm, const bf16* __restrict__ BHd,
                              float* __restrict__ Scol)
{
  const int b = blockIdx.x;          // [0,512)
  const int sd = b >> 8, n = b & 255;
  const int lane = threadIdx.x;      // 64
  const bf16* rowp = (sd ? BHd : BHm) + (size_t)(256+n)*4096;
  float s = 0.f;
  #pragma unroll
  for (int t=0;t<8;t++){
    const uint4 v = *(const uint4*)(rowp + t*512 + lane*8);
    unsigned short u[8]; __builtin_memcpy(u,&v,16);
    #pragma unroll
    for (int jj=0;jj<8;jj++) s += rawb2f(u[jj]);
  }
  #pragma unroll
  for (int off=32; off>0; off>>=1) s += __shfl_down(s, off);
  if (lane==0) Scol[sd*256 + n] = s;
}

// ------------------------------------------------------------ main GEMM -----
// v6: 256 blocks x 512 threads (exactly 1 block/CU), split-K=2.
// w = swizzled id: seg(1) x mt(32) x p(4); block owns disjoint 128x256 slab of
// partial[seg][p] -> plain stores, no atomics, no zero pass.
// Per kt (BK=32): {issue A loads + B asyncs for kt+1} -> compute(kt) ->
// {vmcnt-wait A only, cvt, ds_write} -> __syncthreads.
__global__ __launch_bounds__(512,2) void gemm_kernel(
    const float* __restrict__ bigraph, const float* __restrict__ m_co, const float* __restrict__ d_co,
    const int* __restrict__ central_m, const int* __restrict__ central_d,
    const float* __restrict__ scal,
    const bf16* __restrict__ BHm, const bf16* __restrict__ BHd,
    const bf16* __restrict__ BXm, const bf16* __restrict__ BXd,
    float* __restrict__ partial)
{
  __shared__ __align__(16) bf16 As[2][128*32];   // 2 x 8 KB
  __shared__ __align__(16) bf16 Bs[2][512*32];   // 2 x 32 KB
  const int bid = blockIdx.x;
  // bijective XCD swizzle (256 % 8 == 0): p's 64 blocks land on XCDs {2p,2p+1}
  const int w = (bid & 7)*32 + (bid >> 3);
  const int seg = w & 1, mt = (w >> 1) & 31, p = w >> 6;
  const int s = p & 1;
  const bool maskmode = (p < 2);
  const int k0 = seg*2048;
  const int rowbase = mt*128;
  const float* Asrc; int apitch; int acoff;
  if (p==0){ Asrc = m_co; apitch = 4096; acoff = 0; }
  else if (p==1){ Asrc = d_co; apitch = 4096; acoff = 0; }
  else if (p==2){ Asrc = bigraph; apitch = 8192; acoff = 4096; }
  else { Asrc = bigraph + (size_t)4096*8192; apitch = 8192; acoff = 0; }
  const bf16* B0 = (p==0) ? BHm : (p==1) ? BHd : (p==2) ? BXm : BXd;

  const int tid = threadIdx.x;
  const int lane = tid&63, wv = tid>>6;           // 8 waves
  const int wr = wv>>2, wc = wv&3;                // 2 x 4 wave grid
  const int q = lane>>4, l15 = lane&15;

  // ---- kt-invariant staging geometry (hoisted)
  // A: one 16B chunk per thread
  const int a_row = tid>>2, a_sg = tid&3;
  const int a_g  = a_sg ^ ((a_row>>1)&3);
  const int a_gr = rowbase + a_row;
  const float* a_base = Asrc + (size_t)a_gr*apitch + acoff + a_g*8;  // + kkg per kt
  // B: four async chunks per thread (row/swizzle fixed; col varies with kt)
  int b_roff[4]; int b_ldsoff[4];
  #pragma unroll
  for (int j=0;j<4;j++){
    const int cb = wv*256 + j*64;                 // wave-uniform chunk base
    const int chunk = cb + lane;
    const int row = chunk>>2, sg = chunk&3;
    const int gg = sg ^ ((row>>1)&3);
    b_roff[j] = row*4096 + gg*8;
    b_ldsoff[j] = cb*8;
  }

  floatx4 acc0[4][4], acc1[4][4];
  #pragma unroll
  for (int i=0;i<4;i++)
    #pragma unroll
    for (int j=0;j<4;j++)
      #pragma unroll
      for (int r=0;r<4;r++){ acc0[i][j][r] = 0.f; acc1[i][j][r] = 0.f; }

  // ---- helpers
  auto issueB = [&](int kkg, int buf){
    #pragma unroll
    for (int j=0;j<4;j++)
      async_ld16(B0 + (size_t)b_roff[j] + kkg, &Bs[buf][b_ldsoff[j]]);
  };
  auto writeA = [&](f32x4 a0, f32x4 a1, int kkg, int buf){
    const float av[8] = {a0[0],a0[1],a0[2],a0[3],a1[0],a1[1],a1[2],a1[3]};
    unsigned short u[8];
    if (maskmode){
      const int cbase = kkg + a_g*8;
      #pragma unroll
      for (int jj=0;jj<8;jj++)
        u[jj] = (av[jj]!=0.0f && (cbase+jj)!=a_gr) ? (unsigned short)0x3F80 : (unsigned short)0;
    } else {
      #pragma unroll
      for (int jj=0;jj<8;jj++) u[jj] = f2bu(av[jj]);
    }
    uint4 w4; __builtin_memcpy(&w4,u,16);
    *(uint4*)(&As[buf][tid*8]) = w4;
  };

  // ---- prologue: stage kt=0 into buf 0
  {
    const int kkg = k0;
    const float* ap = a_base + kkg;
    f32x4 a0 = __builtin_nontemporal_load((const f32x4*)ap);
    f32x4 a1 = __builtin_nontemporal_load((const f32x4*)(ap+4));
    issueB(kkg, 0);
    writeA(a0, a1, kkg, 0);
  }
  __syncthreads();

  for (int kt=0; kt<64; kt++){
    const int cur = kt & 1;
    const bool pre = (kt+1 < 64);
    f32x4 a0, a1;
    const int nkkg = k0 + (kt+1)*32;
    if (pre){
      // A loads issued FIRST (oldest in vmcnt queue), then B asyncs:
      // the later vmcnt wait for A leaves B in flight.
      const float* ap = a_base + nkkg;
      a0 = __builtin_nontemporal_load((const f32x4*)ap);
      a1 = __builtin_nontemporal_load((const f32x4*)(ap+4));
      issueB(nkkg, cur^1);
    }
    __builtin_amdgcn_sched_barrier(0);   // pin load-issue above compute

    // ---- compute on buf[cur] (pure LDS + MFMA)
    bf16x8 af[4];
    #pragma unroll
    for (int i=0;i<4;i++){
      const int ra = wr*64 + i*16 + l15;
      af[i] = *(const bf16x8*)&As[cur][ra*32 + ((q ^ ((ra>>1)&3)))*8];
    }
    #pragma unroll
    for (int j=0;j<4;j++){
      const int rb = wc*64 + j*16 + l15;
      const int off = rb*32 + ((q ^ ((rb>>1)&3)))*8;
      const bf16x8 b0 = *(const bf16x8*)&Bs[cur][off];
      const bf16x8 b1 = *(const bf16x8*)&Bs[cur][256*32 + off];
      #pragma unroll
      for (int i=0;i<4;i++){
        acc0[i][j] = __builtin_amdgcn_mfma_f32_16x16x32_bf16(af[i], b0, acc0[i][j], 0,0,0);
        acc1[i][j] = __builtin_amdgcn_mfma_f32_16x16x32_bf16(af[i], b1, acc1[i][j], 0,0,0);
      }
    }
    __builtin_amdgcn_sched_barrier(0);   // pin A-wait/cvt/ds_write below compute

    if (pre) writeA(a0, a1, nkkg, cur^1);   // vmcnt wait covers A only
    __syncthreads();                        // drains B asyncs (hidden above)
  }

  // ---- epilogue: combine groups with row scales, plain stores (disjoint slab)
  const float* scS = scal + (size_t)s*12288;
  const int* cenR = s ? central_d : central_m;
  float* pb = partial + ((size_t)seg*4 + p)*4096*256;
  #pragma unroll
  for (int i=0;i<4;i++){
    #pragma unroll
    for (int r_=0;r_<4;r_++){
      const int rl = rowbase + wr*64 + i*16 + q*4 + r_;
      float w0, w1;
      if (maskmode){ w0 = scS[rl]; w1 = -scS[4096+rl]; }
      else { const float nr = scS[8192+rl]; w0 = nr; w1 = cenR[rl] ? nr : 0.f; }
      #pragma unroll
      for (int j=0;j<4;j++){
        const int gcol = wc*64 + j*16 + l15;
        pb[(size_t)rl*256 + gcol] = w0*acc0[i][j][r_] + w1*acc1[i][j][r_];
      }
    }
  }
}

// -------------------------------------------------------------- reduce ------
// out[r][n] = L0 + (pH0+pH1) + (pX0+pX1) + r1*Scol[n] - r1^2*L2nat
__global__ void reduce_kernel(const float* __restrict__ partial,
                              const float* __restrict__ L0m, const float* __restrict__ L0d,
                              const float* __restrict__ L2nm, const float* __restrict__ L2nd,
                              const float* __restrict__ Scol, const float* __restrict__ scal,
                              float* __restrict__ out)
{
  const int idx = blockIdx.x*blockDim.x + threadIdx.x;   // [0, 524288)
  const int r = idx >> 6;
  const int n4 = (idx & 63) << 2;
  const int s = r >> 12;            // 0: m, 1: d
  const int rl = r & 4095;
  const float r1 = scal[s*12288 + 4096 + rl];
  const size_t rb = (size_t)rl*256 + n4;
  const float4 l0 = *(const float4*)((s? L0d : L0m) + rb);
  const float4 l2 = *(const float4*)((s? L2nd : L2nm) + rb);
  const float4 sc = *(const float4*)(Scol + s*256 + n4);
  const float4 h0 = *(const float4*)(partial + (size_t)(0*4+s)*1048576 + rb);
  const float4 h1 = *(const float4*)(partial + (size_t)(1*4+s)*1048576 + rb);
  const float4 x0 = *(const float4*)(partial + (size_t)(0*4+2+s)*1048576 + rb);
  const float4 x1 = *(const float4*)(partial + (size_t)(1*4+2+s)*1048576 + rb);
  const float r1sq = r1*r1;
  float4 o;
  o.x = l0.x + h0.x+h1.x + x0.x+x1.x + r1*sc.x - r1sq*l2.x;
  o.y = l0.y + h0.y+h1.y + x0.y+x1.y + r1*sc.y - r1sq*l2.y;
  o.z = l0.z + h0.z+h1.z + x0.z+x1.z + r1*sc.z - r1sq*l2.z;
  o.w = l0.w + h0.w+h1.w + x0.w+x1.w + r1*sc.w - r1sq*l2.w;
  *(float4*)(out + (size_t)r*256 + n4) = o;
}

// ---------------------------------------------------------------------------
extern "C" void kernel_launch(void* const* d_in, const int* in_sizes, int n_in,
                              void* d_out, int out_size, void* d_ws, size_t ws_size,
                              hipStream_t stream)
{
  (void)in_sizes; (void)n_in; (void)out_size; (void)ws_size;
  const float* m_d_feat   = (const float*)d_in[0];
  const float* bigraph    = (const float*)d_in[1];
  const float* m_co       = (const float*)d_in[2];
  const float* d_co       = (const float*)d_in[3];
  const float* m_co_deg   = (const float*)d_in[4];
  const float* d_co_deg   = (const float*)d_in[5];
  const float* m_d_degree = (const float*)d_in[6];
  const float* d_m_degree = (const float*)d_in[7];
  const float* Wm = (const float*)d_in[8];
  const float* bm = (const float*)d_in[9];
  const float* Wd = (const float*)d_in[10];
  const float* bd = (const float*)d_in[11];
  const float* Wx = (const float*)d_in[12];
  const float* bx = (const float*)d_in[13];
  const int* central_m = (const int*)d_in[14];
  const int* central_d = (const int*)d_in[15];

  char* ws = (char*)d_ws;
  bf16*  BHm  = (bf16*) (ws + 0);          // [512][4096] bf16 = 4 MB
  bf16*  BHd  = (bf16*) (ws + 4194304);
  bf16*  BXm  = (bf16*) (ws + 8388608);
  bf16*  BXd  = (bf16*) (ws + 12582912);
  float* L0m  = (float*)(ws + 16777216);   // [4096][256] fp32 = 4 MB
  float* L0d  = (float*)(ws + 20971520);
  float* L2nm = (float*)(ws + 25165824);
  float* L2nd = (float*)(ws + 29360128);
  float* Sbuf = (float*)(ws + 33554432);   // 1 MB
  float* bSbuf= (float*)(ws + 34603008);   // 4 KB
  float* scal = (float*)(ws + 34607104);   // 96 KB
  float* Scol = (float*)(ws + 34705408);   // 2 KB
  bf16*  Tm   = (bf16*) (ws + 34707456);   // 8 MB
  bf16*  Td   = (bf16*) (ws + 43096064);   // 8 MB (end 51,484,672)
  float* partial = (float*)(ws + 34707456); // [2][4][4096][256] f32 = 32 MB,
                                            // ALIASES Tm/Td (dead after stage2)

  prep_kernel<<<256, 256, 0, stream>>>(m_co_deg, d_co_deg, m_d_degree, d_m_degree,
                                       Wx, bx, scal, Sbuf, bSbuf);
  stage1_kernel<<<dim3(64,16), 256, 0, stream>>>(m_d_feat, Wm, bm, Wd, bd, Sbuf, bSbuf, scal,
                                                 BHm, BHd, L0m, L0d, L2nm, L2nd, Tm, Td);
  stage2_kernel<<<8192, 256, 0, stream>>>(Tm, Td, central_m, central_d, BXm, BXd);
  colsum_kernel<<<512, 64, 0, stream>>>(BHm, BHd, Scol);
  gemm_kernel<<<256, 512, 0, stream>>>(bigraph, m_co, d_co, central_m, central_d,
                                       scal, BHm, BHd, BXm, BXd, partial);
  reduce_kernel<<<2048, 256, 0, stream>>>(partial, L0m, L0d, L2nm, L2nd, Scol, scal, (float*)d_out);
}

// Round 5
// 548.783 us; speedup vs baseline: 1.1151x; 1.0371x over previous
//
#include <hip/hip_runtime.h>
#include <hip/hip_bf16.h>

// R-GCN v7: gemm counted-wait pipeline (T3+T4) — never vmcnt(0) in main loop.
// v6 post-mortem: 1 block/CU + __syncthreads (=vmcnt(0) drain) exposes B-async
// latency every kt (~30-80 us total). v7:
//  - Bs triple-buffered (3x32KB) + As double (2x8KB) = 112 KB LDS.
//  - B asyncs issued TWO kt ahead; A loads ONE kt ahead, issued AFTER older
//    B(kt+1) and BEFORE B(kt+2): the compiler's vmcnt wait for the A regs
//    (before A's ds_write) forces B(kt+1) complete per-wave, so a raw
//    s_barrier with only lgkmcnt(0) suffices — B(kt+2) stays in flight
//    across the barrier (AITER pattern).
//  - sched_barrier(0) pins {A-issue | B-issue | compute | writeA} phases.
// Everything else (v6 tiles, swizzles, split-K=2 plain-store epilogue,
// stage1/2, colsum, prep, reduce): unchanged.

typedef __bf16 bf16x8 __attribute__((ext_vector_type(8)));
typedef float floatx4 __attribute__((ext_vector_type(4)));
typedef float f32x4 __attribute__((ext_vector_type(4)));
using bf16 = __hip_bfloat16;

#define LDK 72   // stage1 LDS pad

__device__ __forceinline__ float b2f(bf16 x){ return __bfloat162float(x); }
__device__ __forceinline__ bf16 f2b(float f){ return __float2bfloat16(f); }
__device__ __forceinline__ float rawb2f(unsigned short u){
  unsigned int x = ((unsigned int)u) << 16; float f; __builtin_memcpy(&f,&x,4); return f;
}
__device__ __forceinline__ unsigned short f2bu(float f){
  bf16 h = __float2bfloat16(f); unsigned short u; __builtin_memcpy(&u,&h,2); return u;
}
__device__ __forceinline__ uint4 cvt8(float4 a, float4 b){
  unsigned short u[8] = {f2bu(a.x),f2bu(a.y),f2bu(a.z),f2bu(a.w),
                         f2bu(b.x),f2bu(b.y),f2bu(b.z),f2bu(b.w)};
  uint4 v; __builtin_memcpy(&v,u,16); return v;
}
// async global->LDS, 16B per lane; lds dest = wave-uniform base + lane*16
__device__ __forceinline__ void async_ld16(const void* gp, void* lp){
  typedef __attribute__((address_space(1))) const unsigned int GU;
  typedef __attribute__((address_space(3))) unsigned int LU;
  __builtin_amdgcn_global_load_lds((GU*)(unsigned long long)gp,
                                   (LU*)(unsigned int)(unsigned long long)lp,
                                   16, 0, 0);
}

// ---------------------------------------------------------------- prep ------
__global__ void prep_kernel(const float* __restrict__ m_co_deg, const float* __restrict__ d_co_deg,
                            const float* __restrict__ m_d_degree, const float* __restrict__ d_m_degree,
                            const float* __restrict__ Wx, const float* __restrict__ bx,
                            float* __restrict__ scal, float* __restrict__ Sbuf, float* __restrict__ bSbuf)
{
  const int i = blockIdx.x*blockDim.x + threadIdx.x;
  if (i < 4096){
    scal[0*4096+i] = rsqrtf(m_co_deg[2*i]);
    scal[1*4096+i] = rsqrtf(m_co_deg[2*i+1]);
    scal[2*4096+i] = 0.5f / m_d_degree[i];
    scal[3*4096+i] = rsqrtf(d_co_deg[2*i]);
    scal[4*4096+i] = rsqrtf(d_co_deg[2*i+1]);
    scal[5*4096+i] = 0.5f / d_m_degree[i];
  }
  const int pa[4] = {0,2,3,6}, pb[4] = {1,5,4,7};
  if (i < 65536){
    #pragma unroll
    for (int s=0;s<4;s++)
      Sbuf[s*65536+i] = Wx[pa[s]*65536+i] + Wx[pb[s]*65536+i];
  }
  if (i < 256){
    #pragma unroll
    for (int s=0;s<4;s++)
      bSbuf[s*256+i] = bx[pa[s]*256+i] + bx[pb[s]*256+i];
  }
}

// -------------------------------------------------------------- stage 1 -----
__global__ __launch_bounds__(256) void stage1_kernel(
    const float* __restrict__ feat, const float* __restrict__ Wm, const float* __restrict__ bm,
    const float* __restrict__ Wd, const float* __restrict__ bd,
    const float* __restrict__ Sbuf, const float* __restrict__ bSbuf, const float* __restrict__ scal,
    bf16* __restrict__ BHm, bf16* __restrict__ BHd,
    float* __restrict__ L0m, float* __restrict__ L0d,
    float* __restrict__ L2nm, float* __restrict__ L2nd,
    bf16* __restrict__ Tm, bf16* __restrict__ Td)
{
  __shared__ __align__(16) bf16 As[128*LDK];
  __shared__ __align__(16) bf16 Bs[128*LDK];
  const int p = blockIdx.y;
  const int side = p >> 3, widx = p & 7;
  const int bx_ = blockIdx.x;
  const bool modeT = (widx != 0 && widx != 7);
  const float* X = feat + (size_t)side*(4096*256);
  const float* Wb = side ? Wd : Wm;
  const float* W = (widx==0) ? Wb : (widx==7) ? (Wb + 2*65536)
                 : (widx<=2) ? (Wb + widx*65536) : (Sbuf + (widx-3)*65536);
  int rt, ct;
  if (!modeT){ rt = bx_>>1; ct = bx_&1; } else { rt = bx_&1; ct = bx_>>1; }
  const float* Amat = modeT ? W : X;
  const float* Bmat = modeT ? X : W;
  const int arow0 = rt*128, brow0 = ct*128;
  const int tid = threadIdx.x;
  const int lane = tid & 63, wv = tid>>6;
  const int wr = wv>>1, wc = wv&1, q = lane>>4, l15 = lane&15;

  floatx4 acc[4][4];
  #pragma unroll
  for (int i=0;i<4;i++)
    #pragma unroll
    for (int j=0;j<4;j++)
      #pragma unroll
      for (int r=0;r<4;r++) acc[i][j][r] = 0.f;

  for (int kt=0; kt<4; kt++){
    const int c0 = kt*64;
    __syncthreads();
    #pragma unroll
    for (int i=0;i<4;i++){
      const int id = tid + i*256;
      const int row = id>>3, kg = id&7;
      const float* ap = Amat + (size_t)(arow0+row)*256 + c0 + kg*8;
      const float* bp = Bmat + (size_t)(brow0+row)*256 + c0 + kg*8;
      float4 a0 = *(const float4*)ap, a1 = *(const float4*)(ap+4);
      float4 b0 = *(const float4*)bp, b1 = *(const float4*)(bp+4);
      *(uint4*)(&As[row*LDK + kg*8]) = cvt8(a0,a1);
      *(uint4*)(&Bs[row*LDK + kg*8]) = cvt8(b0,b1);
    }
    __syncthreads();
    #pragma unroll
    for (int ki=0; ki<2; ki++){
      bf16x8 af[4], bg[4];
      #pragma unroll
      for (int i=0;i<4;i++) af[i] = *(const bf16x8*)&As[(wr*64 + i*16 + l15)*LDK + ki*32 + q*8];
      #pragma unroll
      for (int j=0;j<4;j++) bg[j] = *(const bf16x8*)&Bs[(wc*64 + j*16 + l15)*LDK + ki*32 + q*8];
      #pragma unroll
      for (int i=0;i<4;i++)
        #pragma unroll
        for (int j=0;j<4;j++)
          acc[i][j] = __builtin_amdgcn_mfma_f32_16x16x32_bf16(af[i], bg[j], acc[i][j], 0,0,0);
    }
  }

  const float* bb = side ? bd : bm;
  const float* bias = (widx==0) ? bb : (widx==7) ? (bb + 512)
                    : (widx<=2) ? (bb + widx*256) : (bSbuf + (widx-3)*256);
  float* outF = nullptr; bf16* outB = nullptr; int pitch = 256; const float* scl = nullptr;
  if (widx==0){ outF = side? L0d : L0m; }
  else if (widx==7){ outF = side? L2nd : L2nm; }
  else if (widx==1){ outB = side? BHd : BHm; pitch = 4096; scl = scal + side*12288; }
  else if (widx==2){ outB = (side? BHd : BHm) + 256*4096; pitch = 4096; scl = scal + side*12288 + 4096; }
  else { outB = (side? Td : Tm) + (widx-3)*(256*4096); pitch = 4096; }

  #pragma unroll
  for (int i=0;i<4;i++){
    #pragma unroll
    for (int j=0;j<4;j++){
      const int gcol = brow0 + wc*64 + j*16 + l15;
      #pragma unroll
      for (int r=0;r<4;r++){
        const int grow = arow0 + wr*64 + i*16 + q*4 + r;
        float v = acc[i][j][r];
        const int nidx = modeT ? grow : gcol;
        v += bias[nidx];
        if (scl) v *= scl[gcol];
        if (outF) outF[(size_t)grow*pitch + gcol] = v;
        else      outB[(size_t)grow*pitch + gcol] = f2b(v);
      }
    }
  }
}

// -------------------------------------------------------------- stage 2 -----
__global__ void stage2_kernel(const bf16* __restrict__ Tm, const bf16* __restrict__ Td,
                              const int* __restrict__ central_m, const int* __restrict__ central_d,
                              bf16* __restrict__ BXm, bf16* __restrict__ BXd)
{
  const int idx = blockIdx.x*blockDim.x + threadIdx.x;   // [0, 2*256*4096)
  const int oside = idx >> 20;
  const int rem = idx & 1048575;
  const int n = rem >> 12;
  const int c = rem & 4095;
  const bf16* T = oside ? Tm : Td;                 // source feats = opposite side
  const int* cen = oside ? central_m : central_d;  // column centrality = source side
  bf16* B = oside ? BXd : BXm;
  const bool cc = cen[c] != 0;
  int v0i, v1i;
  if (!oside){ v0i = cc ? 2 : 3; v1i = cc ? 0 : 1; }   // md: V0 = S34/S67, V1 = S01/S25
  else       { v0i = cc ? 1 : 3; v1i = cc ? 0 : 2; }   // dm: V0 = S25/S67, V1 = S01/S34
  const float v0 = b2f(T[(size_t)v0i*1048576 + (size_t)n*4096 + c]);
  const float v1 = b2f(T[(size_t)v1i*1048576 + (size_t)n*4096 + c]);
  B[(size_t)n*4096 + c]         = f2b(v0);
  B[(size_t)(256+n)*4096 + c]   = f2b(v1 - v0);
}

// -------------------------------------------------------------- colsum ------
__global__ void colsum_kernel(const bf16* __restrict__ BHm, const bf16* __restrict__ BHd,
                              float* __restrict__ Scol)
{
  const int b = blockIdx.x;          // [0,512)
  const int sd = b >> 8, n = b & 255;
  const int lane = threadIdx.x;      // 64
  const bf16* rowp = (sd ? BHd : BHm) + (size_t)(256+n)*4096;
  float s = 0.f;
  #pragma unroll
  for (int t=0;t<8;t++){
    const uint4 v = *(const uint4*)(rowp + t*512 + lane*8);
    unsigned short u[8]; __builtin_memcpy(u,&v,16);
    #pragma unroll
    for (int jj=0;jj<8;jj++) s += rawb2f(u[jj]);
  }
  #pragma unroll
  for (int off=32; off>0; off>>=1) s += __shfl_down(s, off);
  if (lane==0) Scol[sd*256 + n] = s;
}

// ------------------------------------------------------------ main GEMM -----
// v7: 256 blocks x 512 threads, split-K=2, disjoint-slab store epilogue.
// Bs triple-buffered; B prefetch 2 kt ahead; raw s_barrier with lgkmcnt(0)
// only (vmcnt never drained to 0 in the main loop).
__global__ __launch_bounds__(512,2) void gemm_kernel(
    const float* __restrict__ bigraph, const float* __restrict__ m_co, const float* __restrict__ d_co,
    const int* __restrict__ central_m, const int* __restrict__ central_d,
    const float* __restrict__ scal,
    const bf16* __restrict__ BHm, const bf16* __restrict__ BHd,
    const bf16* __restrict__ BXm, const bf16* __restrict__ BXd,
    float* __restrict__ partial)
{
  __shared__ __align__(16) bf16 As[2][128*32];   // 2 x 8 KB
  __shared__ __align__(16) bf16 Bs[3][512*32];   // 3 x 32 KB
  const int bid = blockIdx.x;
  // bijective XCD swizzle (256 % 8 == 0): p's 64 blocks land on XCDs {2p,2p+1}
  const int w = (bid & 7)*32 + (bid >> 3);
  const int seg = w & 1, mt = (w >> 1) & 31, p = w >> 6;
  const int s = p & 1;
  const bool maskmode = (p < 2);
  const int k0 = seg*2048;
  const int rowbase = mt*128;
  const float* Asrc; int apitch; int acoff;
  if (p==0){ Asrc = m_co; apitch = 4096; acoff = 0; }
  else if (p==1){ Asrc = d_co; apitch = 4096; acoff = 0; }
  else if (p==2){ Asrc = bigraph; apitch = 8192; acoff = 4096; }
  else { Asrc = bigraph + (size_t)4096*8192; apitch = 8192; acoff = 0; }
  const bf16* B0 = (p==0) ? BHm : (p==1) ? BHd : (p==2) ? BXm : BXd;

  const int tid = threadIdx.x;
  const int lane = tid&63, wv = tid>>6;           // 8 waves
  const int wr = wv>>2, wc = wv&3;                // 2 x 4 wave grid
  const int q = lane>>4, l15 = lane&15;

  // ---- kt-invariant staging geometry (hoisted)
  // A: one 32B fp32 chunk per thread -> 16B bf16 chunk
  const int a_row = tid>>2, a_sg = tid&3;
  const int a_g  = a_sg ^ ((a_row>>1)&3);
  const int a_gr = rowbase + a_row;
  const float* a_base = Asrc + (size_t)a_gr*apitch + acoff + a_g*8;  // + kkg per kt
  // B: four async chunks per thread (row/swizzle fixed; col varies with kt)
  int b_roff[4]; int b_ldsoff[4];
  #pragma unroll
  for (int j=0;j<4;j++){
    const int cb = wv*256 + j*64;                 // wave-uniform chunk base
    const int chunk = cb + lane;
    const int row = chunk>>2, sg = chunk&3;
    const int gg = sg ^ ((row>>1)&3);
    b_roff[j] = row*4096 + gg*8;
    b_ldsoff[j] = cb*8;
  }
  // compute-side LDS offsets (kt-invariant; add buffer base per kt)
  int af_off[4], bf_off[4];
  #pragma unroll
  for (int i=0;i<4;i++){
    const int ra = wr*64 + i*16 + l15;
    af_off[i] = ra*32 + ((q ^ ((ra>>1)&3)))*8;
  }
  #pragma unroll
  for (int j=0;j<4;j++){
    const int rb = wc*64 + j*16 + l15;
    bf_off[j] = rb*32 + ((q ^ ((rb>>1)&3)))*8;
  }

  floatx4 acc0[4][4], acc1[4][4];
  #pragma unroll
  for (int i=0;i<4;i++)
    #pragma unroll
    for (int j=0;j<4;j++)
      #pragma unroll
      for (int r=0;r<4;r++){ acc0[i][j][r] = 0.f; acc1[i][j][r] = 0.f; }

  // ---- helpers
  auto issueB = [&](int kkg, int buf){
    #pragma unroll
    for (int j=0;j<4;j++)
      async_ld16(B0 + (size_t)b_roff[j] + kkg, &Bs[buf][b_ldsoff[j]]);
  };
  auto writeA = [&](f32x4 a0, f32x4 a1, int kkg, int buf){
    const float av[8] = {a0[0],a0[1],a0[2],a0[3],a1[0],a1[1],a1[2],a1[3]};
    unsigned short u[8];
    if (maskmode){
      const int cbase = kkg + a_g*8;
      #pragma unroll
      for (int jj=0;jj<8;jj++)
        u[jj] = (av[jj]!=0.0f && (cbase+jj)!=a_gr) ? (unsigned short)0x3F80 : (unsigned short)0;
    } else {
      #pragma unroll
      for (int jj=0;jj<8;jj++) u[jj] = f2bu(av[jj]);
    }
    uint4 w4; __builtin_memcpy(&w4,u,16);
    *(uint4*)(&As[buf][tid*8]) = w4;
  };

  // ---- prologue: A(0)+B(0) staged; B(1) issued and left in flight
  {
    const float* ap = a_base + k0;
    f32x4 a0 = __builtin_nontemporal_load((const f32x4*)ap);
    f32x4 a1 = __builtin_nontemporal_load((const f32x4*)(ap+4));
    __builtin_amdgcn_sched_barrier(0);
    issueB(k0, 0);
    issueB(k0 + 32, 1);
    __builtin_amdgcn_sched_barrier(0);
    writeA(a0, a1, k0, 0);                        // compiler waits A regs only
    asm volatile("s_waitcnt vmcnt(4) lgkmcnt(0)" ::: "memory");  // B(0) done, B(1) in flight
    __builtin_amdgcn_s_barrier();
    __builtin_amdgcn_sched_barrier(0);
  }

  int bcur = 0;                                   // Bs buffer for current kt
  for (int kt=0; kt<64; kt++){
    const int curA = kt & 1;
    const bool pre1 = (kt+1 < 64);
    const bool pre2 = (kt+2 < 64);
    f32x4 a0, a1;
    // phase 1: A(kt+1) loads — after B(kt+1) (last iter), before B(kt+2)
    if (pre1){
      const float* ap = a_base + k0 + (kt+1)*32;
      a0 = __builtin_nontemporal_load((const f32x4*)ap);
      a1 = __builtin_nontemporal_load((const f32x4*)(ap+4));
    }
    __builtin_amdgcn_sched_barrier(0);
    // phase 2: B(kt+2) asyncs into buffer (bcur+2)%3
    if (pre2){
      const int bw = (bcur+2 < 3) ? bcur+2 : bcur-1;
      issueB(k0 + (kt+2)*32, bw);
    }
    __builtin_amdgcn_sched_barrier(0);
    // phase 3: compute on As[curA], Bs[bcur] (pure LDS + MFMA)
    {
      const bf16* AsC = &As[curA][0];
      const bf16* BsC = &Bs[bcur][0];
      bf16x8 af[4];
      #pragma unroll
      for (int i=0;i<4;i++) af[i] = *(const bf16x8*)&AsC[af_off[i]];
      #pragma unroll
      for (int j=0;j<4;j++){
        const bf16x8 b0 = *(const bf16x8*)&BsC[bf_off[j]];
        const bf16x8 b1 = *(const bf16x8*)&BsC[256*32 + bf_off[j]];
        #pragma unroll
        for (int i=0;i<4;i++){
          acc0[i][j] = __builtin_amdgcn_mfma_f32_16x16x32_bf16(af[i], b0, acc0[i][j], 0,0,0);
          acc1[i][j] = __builtin_amdgcn_mfma_f32_16x16x32_bf16(af[i], b1, acc1[i][j], 0,0,0);
        }
      }
    }
    __builtin_amdgcn_sched_barrier(0);
    // phase 4: writeA(kt+1) — compiler's vmcnt wait for a0/a1 leaves the 4
    // B(kt+2) asyncs (newest) in flight but forces B(kt+1) (older) complete.
    if (pre1) writeA(a0, a1, k0 + (kt+1)*32, curA^1);
    asm volatile("s_waitcnt lgkmcnt(0)" ::: "memory");
    __builtin_amdgcn_s_barrier();                 // NO vmcnt(0): B(kt+2) rides across
    __builtin_amdgcn_sched_barrier(0);
    bcur = (bcur+1 < 3) ? bcur+1 : 0;
  }

  // ---- epilogue: combine groups with row scales, plain stores (disjoint slab)
  const float* scS = scal + (size_t)s*12288;
  const int* cenR = s ? central_d : central_m;
  float* pb = partial + ((size_t)seg*4 + p)*4096*256;
  #pragma unroll
  for (int i=0;i<4;i++){
    #pragma unroll
    for (int r_=0;r_<4;r_++){
      const int rl = rowbase + wr*64 + i*16 + q*4 + r_;
      float w0, w1;
      if (maskmode){ w0 = scS[rl]; w1 = -scS[4096+rl]; }
      else { const float nr = scS[8192+rl]; w0 = nr; w1 = cenR[rl] ? nr : 0.f; }
      #pragma unroll
      for (int j=0;j<4;j++){
        const int gcol = wc*64 + j*16 + l15;
        pb[(size_t)rl*256 + gcol] = w0*acc0[i][j][r_] + w1*acc1[i][j][r_];
      }
    }
  }
}

// -------------------------------------------------------------- reduce ------
// out[r][n] = L0 + (pH0+pH1) + (pX0+pX1) + r1*Scol[n] - r1^2*L2nat
__global__ void reduce_kernel(const float* __restrict__ partial,
                              const float* __restrict__ L0m, const float* __restrict__ L0d,
                              const float* __restrict__ L2nm, const float* __restrict__ L2nd,
                              const float* __restrict__ Scol, const float* __restrict__ scal,
                              float* __restrict__ out)
{
  const int idx = blockIdx.x*blockDim.x + threadIdx.x;   // [0, 524288)
  const int r = idx >> 6;
  const int n4 = (idx & 63) << 2;
  const int s = r >> 12;            // 0: m, 1: d
  const int rl = r & 4095;
  const float r1 = scal[s*12288 + 4096 + rl];
  const size_t rb = (size_t)rl*256 + n4;
  const float4 l0 = *(const float4*)((s? L0d : L0m) + rb);
  const float4 l2 = *(const float4*)((s? L2nd : L2nm) + rb);
  const float4 sc = *(const float4*)(Scol + s*256 + n4);
  const float4 h0 = *(const float4*)(partial + (size_t)(0*4+s)*1048576 + rb);
  const float4 h1 = *(const float4*)(partial + (size_t)(1*4+s)*1048576 + rb);
  const float4 x0 = *(const float4*)(partial + (size_t)(0*4+2+s)*1048576 + rb);
  const float4 x1 = *(const float4*)(partial + (size_t)(1*4+2+s)*1048576 + rb);
  const float r1sq = r1*r1;
  float4 o;
  o.x = l0.x + h0.x+h1.x + x0.x+x1.x + r1*sc.x - r1sq*l2.x;
  o.y = l0.y + h0.y+h1.y + x0.y+x1.y + r1*sc.y - r1sq*l2.y;
  o.z = l0.z + h0.z+h1.z + x0.z+x1.z + r1*sc.z - r1sq*l2.z;
  o.w = l0.w + h0.w+h1.w + x0.w+x1.w + r1*sc.w - r1sq*l2.w;
  *(float4*)(out + (size_t)r*256 + n4) = o;
}

// ---------------------------------------------------------------------------
extern "C" void kernel_launch(void* const* d_in, const int* in_sizes, int n_in,
                              void* d_out, int out_size, void* d_ws, size_t ws_size,
                              hipStream_t stream)
{
  (void)in_sizes; (void)n_in; (void)out_size; (void)ws_size;
  const float* m_d_feat   = (const float*)d_in[0];
  const float* bigraph    = (const float*)d_in[1];
  const float* m_co       = (const float*)d_in[2];
  const float* d_co       = (const float*)d_in[3];
  const float* m_co_deg   = (const float*)d_in[4];
  const float* d_co_deg   = (const float*)d_in[5];
  const float* m_d_degree = (const float*)d_in[6];
  const float* d_m_degree = (const float*)d_in[7];
  const float* Wm = (const float*)d_in[8];
  const float* bm = (const float*)d_in[9];
  const float* Wd = (const float*)d_in[10];
  const float* bd = (const float*)d_in[11];
  const float* Wx = (const float*)d_in[12];
  const float* bx = (const float*)d_in[13];
  const int* central_m = (const int*)d_in[14];
  const int* central_d = (const int*)d_in[15];

  char* ws = (char*)d_ws;
  bf16*  BHm  = (bf16*) (ws + 0);          // [512][4096] bf16 = 4 MB
  bf16*  BHd  = (bf16*) (ws + 4194304);
  bf16*  BXm  = (bf16*) (ws + 8388608);
  bf16*  BXd  = (bf16*) (ws + 12582912);
  float* L0m  = (float*)(ws + 16777216);   // [4096][256] fp32 = 4 MB
  float* L0d  = (float*)(ws + 20971520);
  float* L2nm = (float*)(ws + 25165824);
  float* L2nd = (float*)(ws + 29360128);
  float* Sbuf = (float*)(ws + 33554432);   // 1 MB
  float* bSbuf= (float*)(ws + 34603008);   // 4 KB
  float* scal = (float*)(ws + 34607104);   // 96 KB
  float* Scol = (float*)(ws + 34705408);   // 2 KB
  bf16*  Tm   = (bf16*) (ws + 34707456);   // 8 MB
  bf16*  Td   = (bf16*) (ws + 43096064);   // 8 MB (end 51,484,672)
  float* partial = (float*)(ws + 34707456); // [2][4][4096][256] f32 = 32 MB,
                                            // ALIASES Tm/Td (dead after stage2)

  prep_kernel<<<256, 256, 0, stream>>>(m_co_deg, d_co_deg, m_d_degree, d_m_degree,
                                       Wx, bx, scal, Sbuf, bSbuf);
  stage1_kernel<<<dim3(64,16), 256, 0, stream>>>(m_d_feat, Wm, bm, Wd, bd, Sbuf, bSbuf, scal,
                                                 BHm, BHd, L0m, L0d, L2nm, L2nd, Tm, Td);
  stage2_kernel<<<8192, 256, 0, stream>>>(Tm, Td, central_m, central_d, BXm, BXd);
  colsum_kernel<<<512, 64, 0, stream>>>(BHm, BHd, Scol);
  gemm_kernel<<<256, 512, 0, stream>>>(bigraph, m_co, d_co, central_m, central_d,
                                       scal, BHm, BHd, BXm, BXd, partial);
  reduce_kernel<<<2048, 256, 0, stream>>>(partial, L0m, L0d, L2nm, L2nd, Scol, scal, (float*)d_out);
}